// Round 3
// baseline (71.538 us; speedup 1.0000x reference)
//
#include <hip/hip_runtime.h>
#include <hip/hip_bf16.h>

// GaussianSmoothing (2,1,192,192,192) f32, separable K=13 sigma=2.
// Pass A blur_wh: fused W+H blur within each z-plane (LDS-staged), x -> d_ws
// Pass B col_blur: D-axis blur, rolling float4 accumulators, d_ws -> d_out

#define DIM 192
#define DIM2 (192 * 192)
#define NIMG 2
#define TOTAL (NIMG * DIM * DIM2)   // 14,155,776 floats

#define GTAPS                                                     \
    constexpr float G[13] = {                                     \
        2.2159242e-03f, 8.7641505e-03f, 2.6995483e-02f,           \
        6.4758800e-02f, 1.2098536e-01f, 1.7603266e-01f,           \
        1.9947114e-01f, 1.7603266e-01f, 1.2098536e-01f,           \
        6.4758800e-02f, 2.6995483e-02f, 8.7641505e-03f,           \
        2.2159242e-03f };

// ---------------------------------------------------------------------------
// Pass A: fused W+H blur of one z-plane y-tile.
//   Block = 512 threads. Tile: full W (192) x YT=64 output rows, one plane.
//   raw:   76 rows (64 + 12 halo) x 208 (8-float zero pads each side) = 63.2 KB
//   wb:    76 rows x 192 W-blurred = 58.4 KB        (total LDS 121.6 KB)
//   Grid = 2 imgs * 192 planes * 3 y-tiles = 1152 blocks.
// All LDS accesses are 16B-aligned float4; lane stride 16B -> conflict-free.
// ---------------------------------------------------------------------------
#define YT 64
#define RAWROWS 76        // YT + 12
#define RAWPITCH 208      // 8 + 192 + 8

__global__ __launch_bounds__(512) void blur_wh(const float* __restrict__ in,
                                               float* __restrict__ out) {
    GTAPS
    __shared__ float raw[RAWROWS * RAWPITCH];   // 15808 floats
    __shared__ float wb[RAWROWS * DIM];         // 14592 floats
    const int t = threadIdx.x;
    const int b = blockIdx.x;
    const int ytile = b % 3;
    const int plane = b / 3;                    // n*192 + z
    const int y0 = ytile * YT;
    const float* __restrict__ src = in + (size_t)plane * DIM2;
    float* __restrict__ dst = out + (size_t)plane * DIM2;

    // zero the x-pads: 4 f4-slots per row (float idx 0,4,200,204 - all 16B aligned)
    if (t < RAWROWS * 4) {
        int r = t >> 2;
        int s = t & 3;
        int col = (s < 2) ? (s * 4) : (200 + (s - 2) * 4);
        *(float4*)&raw[r * RAWPITCH + col] = make_float4(0.f, 0.f, 0.f, 0.f);
    }

    // stage raw rows y0-6 .. y0+69 as f4 quads (76 rows x 48 quads = 3648)
    for (int i = t; i < RAWROWS * 48; i += 512) {
        int r = i / 48;
        int q = i % 48;
        int gy = y0 - 6 + r;
        float4 v = make_float4(0.f, 0.f, 0.f, 0.f);
        if (gy >= 0 && gy < DIM) v = ((const float4*)(src + gy * DIM))[q];
        *(float4*)&raw[r * RAWPITCH + 8 + q * 4] = v;
    }
    __syncthreads();

    // W-blur: 76 rows x 48 output quads. Taps span padded floats [x0+2, x0+17]
    // -> 5 aligned f4 loads starting at padded idx 8+x0-8 = x0 ... x0+16.
    for (int i = t; i < RAWROWS * 48; i += 512) {
        int r = i / 48;
        int q = i % 48;
        const float* rp = &raw[r * RAWPITCH + q * 4];   // padded idx x0+0
        float f[20];
        *(float4*)&f[0]  = *(const float4*)&rp[0];
        *(float4*)&f[4]  = *(const float4*)&rp[4];
        *(float4*)&f[8]  = *(const float4*)&rp[8];
        *(float4*)&f[12] = *(const float4*)&rp[12];
        *(float4*)&f[16] = *(const float4*)&rp[16];
        float4 o;
        float* op = &o.x;
#pragma unroll
        for (int j = 0; j < 4; ++j) {
            float acc = 0.0f;
#pragma unroll
            for (int k = 0; k < 13; ++k) acc += G[k] * f[2 + j + k];
            op[j] = acc;
        }
        *(float4*)&wb[r * DIM + q * 4] = o;
    }
    __syncthreads();

    // H-blur: 64 rows x 48 quads; 13 aligned f4 taps down the wb columns.
    for (int i = t; i < YT * 48; i += 512) {
        int y = i / 48;
        int q = i % 48;
        float4 acc = make_float4(0.f, 0.f, 0.f, 0.f);
#pragma unroll
        for (int k = 0; k < 13; ++k) {
            float4 v = *(const float4*)&wb[(y + k) * DIM + q * 4];
            acc.x += G[k] * v.x;
            acc.y += G[k] * v.y;
            acc.z += G[k] * v.z;
            acc.w += G[k] * v.w;
        }
        ((float4*)(dst + (y0 + y) * DIM))[q] = acc;
    }
}

// ---------------------------------------------------------------------------
// Pass B: blur along D. Each thread owns a float4 column, marches 32 outputs
// (+12 halo) with 13 rolling float4 accumulators (fully unrolled).
//   column c: base_f4 = (c / Q) * M + (c % Q)
//   D pass: Q=9216 (quads/plane), M=1769472 (image, f4), S=9216 (plane, f4)
// ncols = 18432; chunks = 6; block = 128 -> grid = 864.
// ---------------------------------------------------------------------------
template <int Q, int M, int S>
__global__ __launch_bounds__(128) void col_blur(const float4* __restrict__ in,
                                                float4* __restrict__ out) {
    GTAPS
    const int gt = blockIdx.x * 128 + threadIdx.x;
    const int chunk = gt / 18432;          // uniform per block (18432 % 128 == 0)
    const int c = gt % 18432;
    const int base = (c / Q) * M + (c % Q);
    const int d0 = chunk * 32;

    float4 acc[13];
#pragma unroll
    for (int j = 0; j < 13; ++j) acc[j] = make_float4(0.f, 0.f, 0.f, 0.f);

#pragma unroll
    for (int s = 0; s < 44; ++s) {
        const int i = d0 - 6 + s;
        float4 v = make_float4(0.f, 0.f, 0.f, 0.f);
        if (i >= 0 && i < DIM) v = in[base + i * S];
#pragma unroll
        for (int j = 0; j < 13; ++j) {
            const float g = G[12 - j];
            acc[j].x += g * v.x;
            acc[j].y += g * v.y;
            acc[j].z += g * v.z;
            acc[j].w += g * v.w;
        }
        if (s >= 12) out[base + (i - 6) * S] = acc[0];
#pragma unroll
        for (int j = 0; j < 12; ++j) acc[j] = acc[j + 1];
        acc[12] = make_float4(0.f, 0.f, 0.f, 0.f);
    }
}

extern "C" void kernel_launch(void* const* d_in, const int* in_sizes, int n_in,
                              void* d_out, int out_size, void* d_ws, size_t ws_size,
                              hipStream_t stream) {
    const float* x = (const float*)d_in[0];
    float* out = (float*)d_out;
    float* tmp = (float*)d_ws;  // 56.6 MB scratch

    // Pass A: fused W+H, x -> tmp
    blur_wh<<<1152, 512, 0, stream>>>(x, tmp);
    // Pass B: D axis (stride 36864 floats = 9216 f4), tmp -> out
    col_blur<9216, 1769472, 9216><<<864, 128, 0, stream>>>((const float4*)tmp, (float4*)out);
}